// Round 5
// baseline (605.317 us; speedup 1.0000x reference)
//
#include <hip/hip_runtime.h>
#include <math.h>

// Round 11 (= round 10 with compile fix: mix_kernel's encu must be non-const,
// enc role writes it).
// enc/mlp software pipeline across 4 point-chunks:
//  - Points split into 4 chunks of ~256K. Launches: prep, enc(c0),
//    mix(enc c1 | mlp c0), mix(enc c2 | mlp c1), mix(enc c3 | mlp c2),
//    mlp(c3). 3/4 of enc co-runs with mlp: enc is L2-request-bound
//    (14.5/16 req/cyc/XCD, VALU 14%), mlp is latency/VALU/MFMA-bound --
//    complementary resources, so overlap shares the machine.
//  - Mix kernel: role per block-row, Bresenham-interleaved (enc:mlp) so
//    every XCD sees both roles at every point of the dispatch.
//    gridDim.x == 8 keeps bid%8 == bx == XCD pinning for enc.
//  - enc/mlp math unchanged from round 9 (bit-exact output).
// Reference bug replicated: final trilerp is c0*(1-fz) + c1*fy (fy, not fz).

#define BLOCK 256
#define NTAB  (16*524288)
#define PITCH 88

constexpr int      kNL[16] = {16,22,28,37,49,65,85,112,148,195,257,338,446,589,777,1025};
constexpr unsigned kSZ[16] = {4096u,10648u,21952u,50656u,117656u,274632u,
                              524288u,524288u,524288u,524288u,524288u,
                              524288u,524288u,524288u,524288u,524288u};

typedef __attribute__((ext_vector_type(8))) short short8;
typedef __attribute__((ext_vector_type(4))) float float4v;

__device__ __forceinline__ short f2bf(float f) {
    unsigned u = __float_as_uint(f);
    unsigned r = u + 0x7fffu + ((u >> 16) & 1u);   // RNE
    return (short)(r >> 16);
}
__device__ __forceinline__ float bf2f(short h) {
    return __uint_as_float(((unsigned)(unsigned short)h) << 16);
}
__device__ __forceinline__ unsigned pk2(float a, float b) {
    return ((unsigned)(unsigned short)f2bf(b) << 16) | (unsigned)(unsigned short)f2bf(a);
}
// packed table entry: lo16 = feat0, hi16 = feat1 (bf16)
__device__ __forceinline__ float pe0(unsigned u) { return __uint_as_float(u << 16); }
__device__ __forceinline__ float pe1(unsigned u) { return __uint_as_float(u & 0xffff0000u); }

// trilerp over 8 packed corners; vv[c]=x0 corners (y,z)=(c>>1,c&1), vv[4+c]=x1.
__device__ __forceinline__ unsigned trilerp_pack(const unsigned* vv, float fx, float fy, float fz)
{
    const float w0x = 1.f-fx, w0y = 1.f-fy, w0z = 1.f-fz;
    float e0, e1;
    {
        float c00 = pe0(vv[0])*w0x + pe0(vv[4])*fx;
        float c01 = pe0(vv[1])*w0x + pe0(vv[5])*fx;
        float c10 = pe0(vv[2])*w0x + pe0(vv[6])*fx;
        float c11 = pe0(vv[3])*w0x + pe0(vv[7])*fx;
        float c0 = c00*w0y + c10*fy;
        float c1 = c01*w0y + c11*fy;
        e0 = c0*w0z + c1*fy;   // reference bug: fy (not fz)
    }
    {
        float c00 = pe1(vv[0])*w0x + pe1(vv[4])*fx;
        float c01 = pe1(vv[1])*w0x + pe1(vv[5])*fx;
        float c10 = pe1(vv[2])*w0x + pe1(vv[6])*fx;
        float c11 = pe1(vv[3])*w0x + pe1(vv[7])*fx;
        float c0 = c00*w0y + c10*fy;
        float c1 = c01*w0y + c11*fy;
        e1 = c0*w0z + c1*fy;   // reference bug: fy (not fz)
    }
    return pk2(e0, e1);
}

// ================= merged prep kernel =================
__global__ __launch_bounds__(BLOCK)
void prep_all(const float* __restrict__ x, const float* __restrict__ grids,
              const float* __restrict__ w1, const float* __restrict__ w2,
              const float* __restrict__ wc1, const float* __restrict__ wc2,
              const float* __restrict__ wc3,
              float4* __restrict__ pos4, unsigned* __restrict__ tbu,
              uint4* __restrict__ wf, int n, int nTabBlk, int nPosBlk)
{
    const int b = blockIdx.x;
    if (b < nTabBlk) {
        int i = b * BLOCK + threadIdx.x;
        if (i < NTAB) {
            float2 v = ((const float2*)grids)[i];
            tbu[i] = pk2(v.x, v.y);
        }
    } else if (b < nTabBlk + nPosBlk) {
        int i = (b - nTabBlk) * BLOCK + threadIdx.x;
        if (i < n) {
            const float* xr = x + (size_t)i * 19;
            pos4[i] = make_float4(xr[0], xr[1], xr[2], 0.f);
        }
    } else {
        int lane = threadIdx.x;
        if (lane < 64) {
            int cn = lane & 15, q = lane >> 4;
            auto pack8 = [](const float* src, int stride) -> uint4 {
                uint4 r;
                r.x = pk2(src[0*stride], src[1*stride]);
                r.y = pk2(src[2*stride], src[3*stride]);
                r.z = pk2(src[4*stride], src[5*stride]);
                r.w = pk2(src[6*stride], src[7*stride]);
                return r;
            };
            int f = 0;
            for (int nt = 0; nt < 4; ++nt)
                wf[(f++)*64 + lane] = pack8(w1 + (q*8)*64 + nt*16 + cn, 64);
            for (int c = 0; c < 2; ++c)
                wf[(f++)*64 + lane] = pack8(w2 + (c*32 + q*8)*16 + cn, 16);
            for (int nt = 0; nt < 4; ++nt)
                wf[(f++)*64 + lane] = pack8(wc1 + (q*8)*64 + nt*16 + cn, 64);
            for (int c = 0; c < 2; ++c)
                for (int nt = 0; nt < 4; ++nt)
                    wf[(f++)*64 + lane] = pack8(wc2 + (c*32 + q*8)*64 + nt*16 + cn, 64);
            for (int c = 0; c < 2; ++c) {
                if (cn < 3) wf[(f++)*64 + lane] = pack8(wc3 + (c*32 + q*8)*3 + cn, 3);
                else { uint4 z; z.x = z.y = z.z = z.w = 0u; wf[(f++)*64 + lane] = z; }
            }
        }
    }
}

// ================= encode (levels 6..15) =================
template<int L>
__device__ __forceinline__ void gather4(const float4* __restrict__ pos4,
                                        const unsigned* __restrict__ tball,
                                        unsigned* __restrict__ encu,
                                        int n, int p0, int cnt)
{
    constexpr unsigned S = kSZ[L];
    constexpr unsigned H2c = 2654435761u, H3c = 805459861u;
    const unsigned* __restrict__ tbu = tball + (size_t)L * 524288u;

    unsigned vv[4][8];
    float fxa[4], fya[4], fza[4];
    #pragma unroll
    for (int q = 0; q < 4; ++q) {
        if (q >= cnt) continue;
        float4 p = pos4[p0+q];
        const float Rf = (float)kNL[L];
        float ux = p.x*Rf, uy = p.y*Rf, uz = p.z*Rf;
        float gx = floorf(ux), gy = floorf(uy), gz = floorf(uz);
        fxa[q] = ux-gx; fya[q] = uy-gy; fza[q] = uz-gz;
        int ix = (int)gx, iy = (int)gy, iz = (int)gz;

        unsigned tc[4];
        #pragma unroll
        for (int c = 0; c < 4; ++c) {
            int yb = c >> 1, zb = c & 1;
            tc[c] = (unsigned)(iy+yb)*H2c ^ (unsigned)(iz+zb)*H3c;
        }
        if ((ix & 1) == 0) {
            #pragma unroll
            for (int c = 0; c < 4; ++c) {
                unsigned idx0 = ((unsigned)ix ^ tc[c]) & (S-1u);
                uint2 pr = *(const uint2*)(tbu + (idx0 & ~1u));
                unsigned swp = idx0 & 1u;
                vv[q][c]   = swp ? pr.y : pr.x;   // corner x=ix
                vv[q][4+c] = swp ? pr.x : pr.y;   // corner x=ix+1
            }
        } else {
            #pragma unroll
            for (int c = 0; c < 4; ++c) {
                unsigned idx0 = ((unsigned)ix     ^ tc[c]) & (S-1u);
                unsigned idx1 = ((unsigned)(ix+1) ^ tc[c]) & (S-1u);
                vv[q][c]   = tbu[idx0];
                vv[q][4+c] = tbu[idx1];
            }
        }
    }

    unsigned pkd[4];
    #pragma unroll
    for (int q = 0; q < 4; ++q) {
        if (q >= cnt) continue;
        pkd[q] = trilerp_pack(vv[q], fxa[q], fya[q], fza[q]);
    }

    unsigned* d = encu + (size_t)L*n + p0;
    if (cnt == 4) {
        uint4 o; o.x = pkd[0]; o.y = pkd[1]; o.z = pkd[2]; o.w = pkd[3];
        *(uint4*)d = o;
    } else {
        for (int q = 0; q < cnt; ++q) d[q] = pkd[q];
    }
}

// enc body for a point range [base, base+len): phase A rows (levels 6..13 by
// bx==XCD), then phase B rows (levels 14/15 on bx<4 / bx>=4, quarter ranges).
__device__ __forceinline__ void enc_body(int bx, int row, int base, int len, int byAc,
                                         const float4* __restrict__ pos4,
                                         const unsigned* __restrict__ tball,
                                         unsigned* __restrict__ encu, int n)
{
    if (row < byAc) {
        int p0 = base + (row*BLOCK + (int)threadIdx.x) * 4;
        int pend = base + len;
        if (p0 >= pend) return;
        int cnt = min(4, pend - p0);
        switch (bx) {
            case 0: gather4< 6>(pos4,tball,encu,n,p0,cnt); break;
            case 1: gather4< 7>(pos4,tball,encu,n,p0,cnt); break;
            case 2: gather4< 8>(pos4,tball,encu,n,p0,cnt); break;
            case 3: gather4< 9>(pos4,tball,encu,n,p0,cnt); break;
            case 4: gather4<10>(pos4,tball,encu,n,p0,cnt); break;
            case 5: gather4<11>(pos4,tball,encu,n,p0,cnt); break;
            case 6: gather4<12>(pos4,tball,encu,n,p0,cnt); break;
            case 7: gather4<13>(pos4,tball,encu,n,p0,cnt); break;
        }
    } else {
        int q4 = (len + 3) / 4;
        int quarter = bx & 3;
        int jb = base + quarter * q4;
        int je = min(base + len, jb + q4);
        int p0 = jb + ((row-byAc)*BLOCK + (int)threadIdx.x) * 4;
        if (p0 >= je) return;
        int cnt = min(4, je - p0);
        if (bx < 4) gather4<14>(pos4,tball,encu,n,p0,cnt);
        else        gather4<15>(pos4,tball,encu,n,p0,cnt);
    }
}

// ---- levels 0..5 single-point address/issue phase (loads only) ----
template<int LV>
__device__ __forceinline__ void enc_addr(float4 p, const unsigned* __restrict__ tball,
                                         unsigned vv[8], float& fx, float& fy, float& fz)
{
    constexpr int R = kNL[LV];
    constexpr unsigned S = kSZ[LV];
    constexpr unsigned H2c = 2654435761u, H3c = 805459861u;
    const unsigned* __restrict__ tb = tball + (size_t)LV * 524288u;
    const float Rf = (float)R;
    float ux = p.x*Rf, uy = p.y*Rf, uz = p.z*Rf;
    float gx = floorf(ux), gy = floorf(uy), gz = floorf(uz);
    fx = ux-gx; fy = uy-gy; fz = uz-gz;
    int ix = (int)gx, iy = (int)gy, iz = (int)gz;

    if (LV >= 3) {
        unsigned tc[4];
        #pragma unroll
        for (int c = 0; c < 4; ++c) {
            int yb = c >> 1, zb = c & 1;
            tc[c] = (unsigned)(iy+yb)*H2c ^ (unsigned)(iz+zb)*H3c;
        }
        if ((ix & 1) == 0) {
            #pragma unroll
            for (int c = 0; c < 4; ++c) {
                unsigned h0 = (unsigned)ix ^ tc[c];
                unsigned base = (h0 & ~1u) % S;          // even, base+1 < S
                uint2 pr = *(const uint2*)(tb + base);
                unsigned swp = h0 & 1u;
                vv[c]   = swp ? pr.y : pr.x;             // corner x=ix
                vv[4+c] = swp ? pr.x : pr.y;             // corner x=ix+1
            }
        } else {
            #pragma unroll
            for (int c = 0; c < 4; ++c) {
                vv[c]   = tb[(((unsigned)ix)     ^ tc[c]) % S];
                vv[4+c] = tb[(((unsigned)(ix+1)) ^ tc[c]) % S];
            }
        }
    } else {
        #pragma unroll
        for (int j = 0; j < 8; ++j) {
            int ox = ix + ((j>>2)&1);
            int oy = iy + ((j>>1)&1);
            int oz = iz + (j&1);
            vv[j] = tb[(unsigned)((oz*(R*R) + oy*R + ox) % (int)S)];
        }
    }
}

// ================= MFMA MLP body =================
__device__ __forceinline__ short8 ldfrag(const uint4* __restrict__ wf, int f, int lane) {
    union { uint4 u; short8 s; } cv;
    cv.u = wf[f*64 + lane];
    return cv.s;
}

__device__ void mlp_body(const float* __restrict__ x,
                         const float4* __restrict__ pos4,
                         const unsigned* __restrict__ tbu,
                         const unsigned* __restrict__ encu,
                         const uint4* __restrict__ wf,
                         float* __restrict__ out, int n, int blk)
{
    __shared__ unsigned short s_scr[4][2][16*PITCH];
    __shared__ float s_sig[4][16];
    __shared__ float s_col[4][16][4];
    __shared__ float s_dir[4][304];          // 16 x rows (19 floats) per wave
    __shared__ unsigned s_lowB[6][64];       // levels 0..5 packed enc per BLOCK

    const int t = threadIdx.x;
    const int lane = t & 63;
    const int wave = t >> 6;
    const int m = lane & 15;
    const int q = lane >> 4;
    const int cn = m;
    const int pt  = blk + wave*16 + m;
    const int ptc = pt < n ? pt : n - 1;
    const int p0w = blk + wave*16;           // first point of this wave's group

    const float4v zero = {0.f, 0.f, 0.f, 0.f};

    // ---- hoisted encu loads (independent; hide under gather work) ----
    unsigned encv[4];
    #pragma unroll
    for (int i = 0; i < 4; ++i) {
        int lv = q*4 + i;
        if (lv >= 6) encv[i] = encu[(size_t)lv*n + ptc];
    }

    // ---- coalesced stage of this wave's 16 x-rows into LDS ----
    {
        int npts = n - p0w; if (npts > 16) npts = 16; if (npts < 0) npts = 0;
        int nfl = npts * 19;
        const float* xs = x + (size_t)p0w * 19;
        float* sd = s_dir[wave];
        #pragma unroll
        for (int it = 0; it < 5; ++it) {
            int idx = it*64 + lane;
            if (idx < nfl) sd[idx] = xs[idx];
        }
    }

    // ---- levels 0..5 for this block's 64 points, wave-uniform level ----
    {
        int pp = blk + lane; if (pp >= n) pp = n - 1; if (pp < 0) pp = 0;
        float4 p = pos4[pp];
        unsigned vv[8]; float fx, fy, fz;
        switch (wave) {
            case 0:  enc_addr<0>(p, tbu, vv, fx, fy, fz); break;
            case 1:  enc_addr<1>(p, tbu, vv, fx, fy, fz); break;
            case 2:  enc_addr<2>(p, tbu, vv, fx, fy, fz); break;
            default: enc_addr<3>(p, tbu, vv, fx, fy, fz); break;
        }
        s_lowB[wave][lane] = trilerp_pack(vv, fx, fy, fz);
    }
    if (lane < 32) {
        int lv = 4 + (wave >> 1);
        int pb2 = (wave & 1)*32 + lane;      // 0..63 within block
        int pp = blk + pb2; if (pp >= n) pp = n - 1; if (pp < 0) pp = 0;
        float4 p = pos4[pp];
        unsigned vv[8]; float fx, fy, fz;
        if (lv == 4) enc_addr<4>(p, tbu, vv, fx, fy, fz);
        else         enc_addr<5>(p, tbu, vv, fx, fy, fz);
        s_lowB[lv][pb2] = trilerp_pack(vv, fx, fy, fz);
    }
    __syncthreads();

    // ---- layer-1 A fragment: levels q*4..q*4+3 ----
    union { unsigned u[4]; short8 s; } a1;
    #pragma unroll
    for (int i = 0; i < 4; ++i) {
        int lv = q*4 + i;
        if (lv < 6) a1.u[i] = s_lowB[lv][wave*16 + m];
        else        a1.u[i] = encv[i];
    }

    short8 bw1[4], bw2[2], bwc1[4];
    #pragma unroll
    for (int nt = 0; nt < 4; ++nt) bw1[nt] = ldfrag(wf, nt, lane);
    #pragma unroll
    for (int c = 0; c < 2; ++c)    bw2[c]  = ldfrag(wf, 4 + c, lane);
    #pragma unroll
    for (int nt = 0; nt < 4; ++nt) bwc1[nt] = ldfrag(wf, 6 + nt, lane);

    float4v h[4];
    #pragma unroll
    for (int nt = 0; nt < 4; ++nt) {
        h[nt] = __builtin_amdgcn_mfma_f32_16x16x32_bf16(a1.s, bw1[nt], zero, 0, 0, 0);
        #pragma unroll
        for (int r = 0; r < 4; ++r) h[nt][r] = fmaxf(h[nt][r], 0.f);
    }

    unsigned short* sA = &s_scr[wave][0][0];
    unsigned short* sB = &s_scr[wave][1][0];
    #pragma unroll
    for (int nt = 0; nt < 4; ++nt)
        #pragma unroll
        for (int r = 0; r < 4; ++r)
            sA[(q*4+r)*PITCH + nt*16 + cn] = (unsigned short)f2bf(h[nt][r]);
    short8 ah[2];
    #pragma unroll
    for (int c = 0; c < 2; ++c)
        ah[c] = *(const short8*)&sA[m*PITCH + c*32 + q*8];

    float4v o = __builtin_amdgcn_mfma_f32_16x16x32_bf16(ah[0], bw2[0], zero, 0, 0, 0);
    o = __builtin_amdgcn_mfma_f32_16x16x32_bf16(ah[1], bw2[1], o, 0, 0, 0);
    if (cn == 0) {
        #pragma unroll
        for (int r = 0; r < 4; ++r) s_sig[wave][q*4+r] = o[r];
    }

    #pragma unroll
    for (int r = 0; r < 4; ++r)
        sB[(q*4+r)*PITCH + cn] = (unsigned short)f2bf(o[r]);
    short8 ov = *(const short8*)&sB[m*PITCH + (q >= 2 ? (q-2)*8 : 0)];

    union { unsigned u[4]; short8 s; } ci_hi, ci_lo;
    if (q < 2) {
        const float* sd = s_dir[wave];
        int rm = ptc - p0w; if (rm < 0) rm = 0;
        #pragma unroll
        for (int i = 0; i < 4; ++i) {
            float d0 = sd[rm*19 + 3 + q*8 + 2*i];
            float d1 = sd[rm*19 + 3 + q*8 + 2*i + 1];
            short h0 = f2bf(d0), h1 = f2bf(d1);
            ci_hi.u[i] = ((unsigned)(unsigned short)h1 << 16) | (unsigned)(unsigned short)h0;
            short l0 = f2bf(d0 - bf2f(h0)), l1 = f2bf(d1 - bf2f(h1));
            ci_lo.u[i] = ((unsigned)(unsigned short)l1 << 16) | (unsigned)(unsigned short)l0;
        }
    } else {
        ci_hi.s = ov;
        #pragma unroll
        for (int i = 0; i < 4; ++i) ci_lo.u[i] = 0u;
    }

    float4v hc[4];
    #pragma unroll
    for (int nt = 0; nt < 4; ++nt) {
        hc[nt] = __builtin_amdgcn_mfma_f32_16x16x32_bf16(ci_hi.s, bwc1[nt], zero, 0, 0, 0);
        hc[nt] = __builtin_amdgcn_mfma_f32_16x16x32_bf16(ci_lo.s, bwc1[nt], hc[nt], 0, 0, 0);
        #pragma unroll
        for (int r = 0; r < 4; ++r) hc[nt][r] = fmaxf(hc[nt][r], 0.f);
    }

    short8 bwc2[2][4], bwc3[2];
    #pragma unroll
    for (int c = 0; c < 2; ++c)
        #pragma unroll
        for (int nt = 0; nt < 4; ++nt)
            bwc2[c][nt] = ldfrag(wf, 10 + c*4 + nt, lane);
    #pragma unroll
    for (int c = 0; c < 2; ++c) bwc3[c] = ldfrag(wf, 18 + c, lane);

    #pragma unroll
    for (int nt = 0; nt < 4; ++nt)
        #pragma unroll
        for (int r = 0; r < 4; ++r) {
            float v = hc[nt][r];
            short hi = f2bf(v);
            sA[(q*4+r)*PITCH + nt*16 + cn] = (unsigned short)hi;
            sB[(q*4+r)*PITCH + nt*16 + cn] = (unsigned short)f2bf(v - bf2f(hi));
        }
    short8 ghi[2], glo[2];
    #pragma unroll
    for (int c = 0; c < 2; ++c) {
        ghi[c] = *(const short8*)&sA[m*PITCH + c*32 + q*8];
        glo[c] = *(const short8*)&sB[m*PITCH + c*32 + q*8];
    }

    float4v g[4];
    #pragma unroll
    for (int nt = 0; nt < 4; ++nt) {
        float4v acc = __builtin_amdgcn_mfma_f32_16x16x32_bf16(ghi[0], bwc2[0][nt], zero, 0, 0, 0);
        acc = __builtin_amdgcn_mfma_f32_16x16x32_bf16(glo[0], bwc2[0][nt], acc, 0, 0, 0);
        acc = __builtin_amdgcn_mfma_f32_16x16x32_bf16(ghi[1], bwc2[1][nt], acc, 0, 0, 0);
        acc = __builtin_amdgcn_mfma_f32_16x16x32_bf16(glo[1], bwc2[1][nt], acc, 0, 0, 0);
        #pragma unroll
        for (int r = 0; r < 4; ++r) acc[r] = fmaxf(acc[r], 0.f);
        g[nt] = acc;
    }

    #pragma unroll
    for (int nt = 0; nt < 4; ++nt)
        #pragma unroll
        for (int r = 0; r < 4; ++r) {
            float v = g[nt][r];
            short hi = f2bf(v);
            sA[(q*4+r)*PITCH + nt*16 + cn] = (unsigned short)hi;
            sB[(q*4+r)*PITCH + nt*16 + cn] = (unsigned short)f2bf(v - bf2f(hi));
        }
    short8 uhi[2], ulo[2];
    #pragma unroll
    for (int c = 0; c < 2; ++c) {
        uhi[c] = *(const short8*)&sA[m*PITCH + c*32 + q*8];
        ulo[c] = *(const short8*)&sB[m*PITCH + c*32 + q*8];
    }

    float4v col = __builtin_amdgcn_mfma_f32_16x16x32_bf16(uhi[0], bwc3[0], zero, 0, 0, 0);
    col = __builtin_amdgcn_mfma_f32_16x16x32_bf16(ulo[0], bwc3[0], col, 0, 0, 0);
    col = __builtin_amdgcn_mfma_f32_16x16x32_bf16(uhi[1], bwc3[1], col, 0, 0, 0);
    col = __builtin_amdgcn_mfma_f32_16x16x32_bf16(ulo[1], bwc3[1], col, 0, 0, 0);
    #pragma unroll
    for (int r = 0; r < 4; ++r)
        col[r] = 1.f / (1.f + __expf(-col[r]));

    if (cn < 3) {
        #pragma unroll
        for (int r = 0; r < 4; ++r) s_col[wave][q*4+r][cn] = col[r];
    }

    __builtin_amdgcn_s_waitcnt(0);
    int pfi = lane >> 2, c4 = lane & 3;
    int pout = blk + wave*16 + pfi;
    if (pout < n) {
        float v = (c4 == 3) ? s_sig[wave][pfi] : s_col[wave][pfi][c4];
        out[(size_t)pout*4 + c4] = v;
    }
}

// ================= pipeline kernels =================
__global__ __launch_bounds__(BLOCK)
void enc_chunk(const float4* __restrict__ pos4, const unsigned* __restrict__ tball,
               unsigned* __restrict__ encu, int n, int base, int len, int byAc)
{
    enc_body((int)blockIdx.x, (int)blockIdx.y, base, len, byAc, pos4, tball, encu, n);
}

// mix: row r is enc (chunk [encBase,encBase+encLen)) or mlp (chunk [mlpBase,mlpEnd))
// via Bresenham interleave of E enc rows among R total rows.
// NOTE: encu is non-const (enc role writes it; mlp role only reads).
__global__ __launch_bounds__(BLOCK)
void mix_kernel(const float* __restrict__ x, const float4* __restrict__ pos4,
                const unsigned* __restrict__ tbu, unsigned* __restrict__ encu,
                const uint4* __restrict__ wf, float* __restrict__ out, int n,
                int encBase, int encLen, int byAc, int E, int R,
                int mlpBase, int mlpEnd)
{
    const int r = blockIdx.y;
    const int er  = (int)(((long long)r     * E) / R);
    const int er1 = (int)(((long long)(r+1) * E) / R);
    if (er1 > er) {
        enc_body((int)blockIdx.x, er, encBase, encLen, byAc, pos4, tbu, encu, n);
    } else {
        int mrow = r - er;
        int blk = mlpBase + (mrow*8 + (int)blockIdx.x)*64;
        if (blk >= mlpEnd) return;
        mlp_body(x, pos4, tbu, encu, wf, out, n, blk);
    }
}

__global__ __launch_bounds__(BLOCK)
void mlp_chunk(const float* __restrict__ x, const float4* __restrict__ pos4,
               const unsigned* __restrict__ tbu, const unsigned* __restrict__ encu,
               const uint4* __restrict__ wf, float* __restrict__ out, int n,
               int pbase, int pend)
{
    int blk = pbase + (int)blockIdx.x*64;
    if (blk >= pend) return;
    mlp_body(x, pos4, tbu, encu, wf, out, n, blk);
}

// ================= launch =================
extern "C" void kernel_launch(void* const* d_in, const int* in_sizes, int n_in,
                              void* d_out, int out_size, void* d_ws, size_t ws_size,
                              hipStream_t stream) {
    const float* x     = (const float*)d_in[0];
    const float* grids = (const float*)d_in[1];
    const float* w1    = (const float*)d_in[2];
    const float* w2    = (const float*)d_in[3];
    const float* wc1   = (const float*)d_in[4];
    const float* wc2   = (const float*)d_in[5];
    const float* wc3   = (const float*)d_in[6];
    float* out = (float*)d_out;

    int n = in_sizes[0] / 19;
    size_t encB = (size_t)16 * n * sizeof(unsigned);       // 64 MB
    size_t posB = (size_t)n * sizeof(float4);              // 16 MB
    size_t tabB = (size_t)NTAB * sizeof(unsigned);         // 33.5 MB

    char* p = (char*)d_ws;
    unsigned* encu = (unsigned*)p;
    float4*   pos4 = (float4*)(p + encB);
    unsigned* tbu  = (unsigned*)(p + encB + posB);
    uint4*    wf   = (uint4*)(p + encB + posB + tabB);

    int nTabBlk = (NTAB + BLOCK - 1) / BLOCK;
    int nPosBlk = (n + BLOCK - 1) / BLOCK;
    prep_all<<<nTabBlk + nPosBlk + 1, BLOCK, 0, stream>>>(
        x, grids, w1, w2, wc1, wc2, wc3, pos4, tbu, wf, n, nTabBlk, nPosBlk);

    // 4-chunk pipeline: enc(c0); mix(enc c | mlp c-1) x3; mlp(c3).
    const int NCH = 4;
    int nc = ((n + NCH - 1) / NCH + 1023) & ~1023;         // chunk size, x1024
    int cb[NCH+1];
    for (int i = 0; i <= NCH; ++i) {
        long long b = (long long)i * nc;
        cb[i] = (int)(b < n ? b : n);
    }

    auto encRows = [&](int len, int& byAc) {
        byAc = (len + BLOCK*4 - 1) / (BLOCK*4);
        int q4 = (len + 3) / 4;
        int byBc = (q4 + BLOCK*4 - 1) / (BLOCK*4);
        return byAc + byBc;
    };

    // enc chunk 0
    {
        int len0 = cb[1] - cb[0];
        if (len0 > 0) {
            int byA0; int E0 = encRows(len0, byA0);
            enc_chunk<<<dim3(8, E0), BLOCK, 0, stream>>>(pos4, tbu, encu, n, cb[0], len0, byA0);
        }
    }
    // mixed middle stages
    for (int c = 1; c < NCH; ++c) {
        int lenE = cb[c+1] - cb[c];
        int lenM = cb[c] - cb[c-1];
        int Mrows = (lenM + 511) / 512;
        if (lenE > 0 && lenM > 0) {
            int byAc; int E = encRows(lenE, byAc);
            int R = E + Mrows;
            mix_kernel<<<dim3(8, R), BLOCK, 0, stream>>>(
                x, pos4, tbu, encu, wf, out, n,
                cb[c], lenE, byAc, E, R, cb[c-1], cb[c]);
        } else if (lenM > 0) {
            mlp_chunk<<<dim3(Mrows*8), BLOCK, 0, stream>>>(
                x, pos4, tbu, encu, wf, out, n, cb[c-1], cb[c]);
        } else if (lenE > 0) {
            int byAc; int E = encRows(lenE, byAc);
            enc_chunk<<<dim3(8, E), BLOCK, 0, stream>>>(pos4, tbu, encu, n, cb[c], lenE, byAc);
        }
    }
    // mlp tail chunk
    {
        int lenT = cb[NCH] - cb[NCH-1];
        if (lenT > 0) {
            int Mt = (lenT + 63) / 64;
            mlp_chunk<<<dim3(Mt), BLOCK, 0, stream>>>(
                x, pos4, tbu, encu, wf, out, n, cb[NCH-1], cb[NCH]);
        }
    }
}

// Round 6
// 592.155 us; speedup vs baseline: 1.0222x; 1.0222x over previous
//
#include <hip/hip_runtime.h>
#include <math.h>

// Round 12: pipeline retry with occupancy fix.
//  - Round 11 failure: mix kernel LDS=30208B -> 5 blocks/CU -> enc-role
//    starved (37.6% occupancy vs 75% standalone); mix 115us vs 105 serial.
//  - Fix: slim mlp LDS 30208 -> 21248B => 7 blocks/CU:
//      * PITCH 88 -> 72 (b128 reads still evenly spread: start dword
//        4(m+q)%32; ushort writes 2-way = free).
//      * s_dir dropped; direction inputs = 8 scalar x loads per q<2 lane,
//        HOISTED to kernel top (latency hidden under low-level gathers).
//  - prep: conv_tables 2 entries/lane (float4 in, uint2 out).
//  - Math unchanged (bit-exact vs round 9/11).
// Reference bug replicated: final trilerp is c0*(1-fz) + c1*fy (fy, not fz).

#define BLOCK 256
#define NTAB  (16*524288)
#define PITCH 72

constexpr int      kNL[16] = {16,22,28,37,49,65,85,112,148,195,257,338,446,589,777,1025};
constexpr unsigned kSZ[16] = {4096u,10648u,21952u,50656u,117656u,274632u,
                              524288u,524288u,524288u,524288u,524288u,
                              524288u,524288u,524288u,524288u,524288u};

typedef __attribute__((ext_vector_type(8))) short short8;
typedef __attribute__((ext_vector_type(4))) float float4v;

__device__ __forceinline__ short f2bf(float f) {
    unsigned u = __float_as_uint(f);
    unsigned r = u + 0x7fffu + ((u >> 16) & 1u);   // RNE
    return (short)(r >> 16);
}
__device__ __forceinline__ float bf2f(short h) {
    return __uint_as_float(((unsigned)(unsigned short)h) << 16);
}
__device__ __forceinline__ unsigned pk2(float a, float b) {
    return ((unsigned)(unsigned short)f2bf(b) << 16) | (unsigned)(unsigned short)f2bf(a);
}
// packed table entry: lo16 = feat0, hi16 = feat1 (bf16)
__device__ __forceinline__ float pe0(unsigned u) { return __uint_as_float(u << 16); }
__device__ __forceinline__ float pe1(unsigned u) { return __uint_as_float(u & 0xffff0000u); }

// trilerp over 8 packed corners; vv[c]=x0 corners (y,z)=(c>>1,c&1), vv[4+c]=x1.
__device__ __forceinline__ unsigned trilerp_pack(const unsigned* vv, float fx, float fy, float fz)
{
    const float w0x = 1.f-fx, w0y = 1.f-fy, w0z = 1.f-fz;
    float e0, e1;
    {
        float c00 = pe0(vv[0])*w0x + pe0(vv[4])*fx;
        float c01 = pe0(vv[1])*w0x + pe0(vv[5])*fx;
        float c10 = pe0(vv[2])*w0x + pe0(vv[6])*fx;
        float c11 = pe0(vv[3])*w0x + pe0(vv[7])*fx;
        float c0 = c00*w0y + c10*fy;
        float c1 = c01*w0y + c11*fy;
        e0 = c0*w0z + c1*fy;   // reference bug: fy (not fz)
    }
    {
        float c00 = pe1(vv[0])*w0x + pe1(vv[4])*fx;
        float c01 = pe1(vv[1])*w0x + pe1(vv[5])*fx;
        float c10 = pe1(vv[2])*w0x + pe1(vv[6])*fx;
        float c11 = pe1(vv[3])*w0x + pe1(vv[7])*fx;
        float c0 = c00*w0y + c10*fy;
        float c1 = c01*w0y + c11*fy;
        e1 = c0*w0z + c1*fy;   // reference bug: fy (not fz)
    }
    return pk2(e0, e1);
}

// ================= merged prep kernel =================
__global__ __launch_bounds__(BLOCK)
void prep_all(const float* __restrict__ x, const float* __restrict__ grids,
              const float* __restrict__ w1, const float* __restrict__ w2,
              const float* __restrict__ wc1, const float* __restrict__ wc2,
              const float* __restrict__ wc3,
              float4* __restrict__ pos4, unsigned* __restrict__ tbu,
              uint4* __restrict__ wf, int n, int nTabBlk, int nPosBlk)
{
    const int b = blockIdx.x;
    if (b < nTabBlk) {
        int i = b * BLOCK + threadIdx.x;           // 2 entries per lane
        if (i < NTAB/2) {
            float4 v = ((const float4*)grids)[i];
            uint2 o;
            o.x = pk2(v.x, v.y);
            o.y = pk2(v.z, v.w);
            ((uint2*)tbu)[i] = o;
        }
    } else if (b < nTabBlk + nPosBlk) {
        int i = (b - nTabBlk) * BLOCK + threadIdx.x;
        if (i < n) {
            const float* xr = x + (size_t)i * 19;
            pos4[i] = make_float4(xr[0], xr[1], xr[2], 0.f);
        }
    } else {
        int lane = threadIdx.x;
        if (lane < 64) {
            int cn = lane & 15, q = lane >> 4;
            auto pack8 = [](const float* src, int stride) -> uint4 {
                uint4 r;
                r.x = pk2(src[0*stride], src[1*stride]);
                r.y = pk2(src[2*stride], src[3*stride]);
                r.z = pk2(src[4*stride], src[5*stride]);
                r.w = pk2(src[6*stride], src[7*stride]);
                return r;
            };
            int f = 0;
            for (int nt = 0; nt < 4; ++nt)
                wf[(f++)*64 + lane] = pack8(w1 + (q*8)*64 + nt*16 + cn, 64);
            for (int c = 0; c < 2; ++c)
                wf[(f++)*64 + lane] = pack8(w2 + (c*32 + q*8)*16 + cn, 16);
            for (int nt = 0; nt < 4; ++nt)
                wf[(f++)*64 + lane] = pack8(wc1 + (q*8)*64 + nt*16 + cn, 64);
            for (int c = 0; c < 2; ++c)
                for (int nt = 0; nt < 4; ++nt)
                    wf[(f++)*64 + lane] = pack8(wc2 + (c*32 + q*8)*64 + nt*16 + cn, 64);
            for (int c = 0; c < 2; ++c) {
                if (cn < 3) wf[(f++)*64 + lane] = pack8(wc3 + (c*32 + q*8)*3 + cn, 3);
                else { uint4 z; z.x = z.y = z.z = z.w = 0u; wf[(f++)*64 + lane] = z; }
            }
        }
    }
}

// ================= encode (levels 6..15) =================
template<int L>
__device__ __forceinline__ void gather4(const float4* __restrict__ pos4,
                                        const unsigned* __restrict__ tball,
                                        unsigned* __restrict__ encu,
                                        int n, int p0, int cnt)
{
    constexpr unsigned S = kSZ[L];
    constexpr unsigned H2c = 2654435761u, H3c = 805459861u;
    const unsigned* __restrict__ tbu = tball + (size_t)L * 524288u;

    unsigned vv[4][8];
    float fxa[4], fya[4], fza[4];
    #pragma unroll
    for (int q = 0; q < 4; ++q) {
        if (q >= cnt) continue;
        float4 p = pos4[p0+q];
        const float Rf = (float)kNL[L];
        float ux = p.x*Rf, uy = p.y*Rf, uz = p.z*Rf;
        float gx = floorf(ux), gy = floorf(uy), gz = floorf(uz);
        fxa[q] = ux-gx; fya[q] = uy-gy; fza[q] = uz-gz;
        int ix = (int)gx, iy = (int)gy, iz = (int)gz;

        unsigned tc[4];
        #pragma unroll
        for (int c = 0; c < 4; ++c) {
            int yb = c >> 1, zb = c & 1;
            tc[c] = (unsigned)(iy+yb)*H2c ^ (unsigned)(iz+zb)*H3c;
        }
        if ((ix & 1) == 0) {
            #pragma unroll
            for (int c = 0; c < 4; ++c) {
                unsigned idx0 = ((unsigned)ix ^ tc[c]) & (S-1u);
                uint2 pr = *(const uint2*)(tbu + (idx0 & ~1u));
                unsigned swp = idx0 & 1u;
                vv[q][c]   = swp ? pr.y : pr.x;   // corner x=ix
                vv[q][4+c] = swp ? pr.x : pr.y;   // corner x=ix+1
            }
        } else {
            #pragma unroll
            for (int c = 0; c < 4; ++c) {
                unsigned idx0 = ((unsigned)ix     ^ tc[c]) & (S-1u);
                unsigned idx1 = ((unsigned)(ix+1) ^ tc[c]) & (S-1u);
                vv[q][c]   = tbu[idx0];
                vv[q][4+c] = tbu[idx1];
            }
        }
    }

    unsigned pkd[4];
    #pragma unroll
    for (int q = 0; q < 4; ++q) {
        if (q >= cnt) continue;
        pkd[q] = trilerp_pack(vv[q], fxa[q], fya[q], fza[q]);
    }

    unsigned* d = encu + (size_t)L*n + p0;
    if (cnt == 4) {
        uint4 o; o.x = pkd[0]; o.y = pkd[1]; o.z = pkd[2]; o.w = pkd[3];
        *(uint4*)d = o;
    } else {
        for (int q = 0; q < cnt; ++q) d[q] = pkd[q];
    }
}

// enc body for a point range [base, base+len): phase A rows (levels 6..13 by
// bx==XCD), then phase B rows (levels 14/15 on bx<4 / bx>=4, quarter ranges).
__device__ __forceinline__ void enc_body(int bx, int row, int base, int len, int byAc,
                                         const float4* __restrict__ pos4,
                                         const unsigned* __restrict__ tball,
                                         unsigned* __restrict__ encu, int n)
{
    if (row < byAc) {
        int p0 = base + (row*BLOCK + (int)threadIdx.x) * 4;
        int pend = base + len;
        if (p0 >= pend) return;
        int cnt = min(4, pend - p0);
        switch (bx) {
            case 0: gather4< 6>(pos4,tball,encu,n,p0,cnt); break;
            case 1: gather4< 7>(pos4,tball,encu,n,p0,cnt); break;
            case 2: gather4< 8>(pos4,tball,encu,n,p0,cnt); break;
            case 3: gather4< 9>(pos4,tball,encu,n,p0,cnt); break;
            case 4: gather4<10>(pos4,tball,encu,n,p0,cnt); break;
            case 5: gather4<11>(pos4,tball,encu,n,p0,cnt); break;
            case 6: gather4<12>(pos4,tball,encu,n,p0,cnt); break;
            case 7: gather4<13>(pos4,tball,encu,n,p0,cnt); break;
        }
    } else {
        int q4 = (len + 3) / 4;
        int quarter = bx & 3;
        int jb = base + quarter * q4;
        int je = min(base + len, jb + q4);
        int p0 = jb + ((row-byAc)*BLOCK + (int)threadIdx.x) * 4;
        if (p0 >= je) return;
        int cnt = min(4, je - p0);
        if (bx < 4) gather4<14>(pos4,tball,encu,n,p0,cnt);
        else        gather4<15>(pos4,tball,encu,n,p0,cnt);
    }
}

// ---- levels 0..5 single-point address/issue phase (loads only) ----
template<int LV>
__device__ __forceinline__ void enc_addr(float4 p, const unsigned* __restrict__ tball,
                                         unsigned vv[8], float& fx, float& fy, float& fz)
{
    constexpr int R = kNL[LV];
    constexpr unsigned S = kSZ[LV];
    constexpr unsigned H2c = 2654435761u, H3c = 805459861u;
    const unsigned* __restrict__ tb = tball + (size_t)LV * 524288u;
    const float Rf = (float)R;
    float ux = p.x*Rf, uy = p.y*Rf, uz = p.z*Rf;
    float gx = floorf(ux), gy = floorf(uy), gz = floorf(uz);
    fx = ux-gx; fy = uy-gy; fz = uz-gz;
    int ix = (int)gx, iy = (int)gy, iz = (int)gz;

    if (LV >= 3) {
        unsigned tc[4];
        #pragma unroll
        for (int c = 0; c < 4; ++c) {
            int yb = c >> 1, zb = c & 1;
            tc[c] = (unsigned)(iy+yb)*H2c ^ (unsigned)(iz+zb)*H3c;
        }
        if ((ix & 1) == 0) {
            #pragma unroll
            for (int c = 0; c < 4; ++c) {
                unsigned h0 = (unsigned)ix ^ tc[c];
                unsigned base = (h0 & ~1u) % S;          // even, base+1 < S
                uint2 pr = *(const uint2*)(tb + base);
                unsigned swp = h0 & 1u;
                vv[c]   = swp ? pr.y : pr.x;             // corner x=ix
                vv[4+c] = swp ? pr.x : pr.y;             // corner x=ix+1
            }
        } else {
            #pragma unroll
            for (int c = 0; c < 4; ++c) {
                vv[c]   = tb[(((unsigned)ix)     ^ tc[c]) % S];
                vv[4+c] = tb[(((unsigned)(ix+1)) ^ tc[c]) % S];
            }
        }
    } else {
        #pragma unroll
        for (int j = 0; j < 8; ++j) {
            int ox = ix + ((j>>2)&1);
            int oy = iy + ((j>>1)&1);
            int oz = iz + (j&1);
            vv[j] = tb[(unsigned)((oz*(R*R) + oy*R + ox) % (int)S)];
        }
    }
}

// ================= MFMA MLP body =================
__device__ __forceinline__ short8 ldfrag(const uint4* __restrict__ wf, int f, int lane) {
    union { uint4 u; short8 s; } cv;
    cv.u = wf[f*64 + lane];
    return cv.s;
}

__device__ void mlp_body(const float* __restrict__ x,
                         const float4* __restrict__ pos4,
                         const unsigned* __restrict__ tbu,
                         const unsigned* __restrict__ encu,
                         const uint4* __restrict__ wf,
                         float* __restrict__ out, int n, int blk)
{
    __shared__ unsigned short s_scr[4][2][16*PITCH];   // 18432 B
    __shared__ float s_sig[4][16];                     //   256 B
    __shared__ float s_col[4][16][4];                  //  1024 B
    __shared__ unsigned s_lowB[6][64];                 //  1536 B  (21248 total)

    const int t = threadIdx.x;
    const int lane = t & 63;
    const int wave = t >> 6;
    const int m = lane & 15;
    const int q = lane >> 4;
    const int cn = m;
    const int pt  = blk + wave*16 + m;
    const int ptc = pt < n ? pt : n - 1;

    const float4v zero = {0.f, 0.f, 0.f, 0.f};

    // ---- hoisted independent loads: encu levels + direction floats ----
    unsigned encv[4];
    #pragma unroll
    for (int i = 0; i < 4; ++i) {
        int lv = q*4 + i;
        if (lv >= 6) encv[i] = encu[(size_t)lv*n + ptc];
    }
    float dv[8];
    if (q < 2) {
        #pragma unroll
        for (int i = 0; i < 8; ++i)
            dv[i] = x[(size_t)ptc*19 + 3 + q*8 + i];
    }

    // ---- levels 0..5 for this block's 64 points, wave-uniform level ----
    {
        int pp = blk + lane; if (pp >= n) pp = n - 1; if (pp < 0) pp = 0;
        float4 p = pos4[pp];
        unsigned vv[8]; float fx, fy, fz;
        switch (wave) {
            case 0:  enc_addr<0>(p, tbu, vv, fx, fy, fz); break;
            case 1:  enc_addr<1>(p, tbu, vv, fx, fy, fz); break;
            case 2:  enc_addr<2>(p, tbu, vv, fx, fy, fz); break;
            default: enc_addr<3>(p, tbu, vv, fx, fy, fz); break;
        }
        s_lowB[wave][lane] = trilerp_pack(vv, fx, fy, fz);
    }
    if (lane < 32) {
        int lv = 4 + (wave >> 1);
        int pb2 = (wave & 1)*32 + lane;      // 0..63 within block
        int pp = blk + pb2; if (pp >= n) pp = n - 1; if (pp < 0) pp = 0;
        float4 p = pos4[pp];
        unsigned vv[8]; float fx, fy, fz;
        if (lv == 4) enc_addr<4>(p, tbu, vv, fx, fy, fz);
        else         enc_addr<5>(p, tbu, vv, fx, fy, fz);
        s_lowB[lv][pb2] = trilerp_pack(vv, fx, fy, fz);
    }
    __syncthreads();

    // ---- layer-1 A fragment: levels q*4..q*4+3 ----
    union { unsigned u[4]; short8 s; } a1;
    #pragma unroll
    for (int i = 0; i < 4; ++i) {
        int lv = q*4 + i;
        if (lv < 6) a1.u[i] = s_lowB[lv][wave*16 + m];
        else        a1.u[i] = encv[i];
    }

    short8 bw1[4], bw2[2], bwc1[4];
    #pragma unroll
    for (int nt = 0; nt < 4; ++nt) bw1[nt] = ldfrag(wf, nt, lane);
    #pragma unroll
    for (int c = 0; c < 2; ++c)    bw2[c]  = ldfrag(wf, 4 + c, lane);
    #pragma unroll
    for (int nt = 0; nt < 4; ++nt) bwc1[nt] = ldfrag(wf, 6 + nt, lane);

    float4v h[4];
    #pragma unroll
    for (int nt = 0; nt < 4; ++nt) {
        h[nt] = __builtin_amdgcn_mfma_f32_16x16x32_bf16(a1.s, bw1[nt], zero, 0, 0, 0);
        #pragma unroll
        for (int r = 0; r < 4; ++r) h[nt][r] = fmaxf(h[nt][r], 0.f);
    }

    unsigned short* sA = &s_scr[wave][0][0];
    unsigned short* sB = &s_scr[wave][1][0];
    #pragma unroll
    for (int nt = 0; nt < 4; ++nt)
        #pragma unroll
        for (int r = 0; r < 4; ++r)
            sA[(q*4+r)*PITCH + nt*16 + cn] = (unsigned short)f2bf(h[nt][r]);
    short8 ah[2];
    #pragma unroll
    for (int c = 0; c < 2; ++c)
        ah[c] = *(const short8*)&sA[m*PITCH + c*32 + q*8];

    float4v o = __builtin_amdgcn_mfma_f32_16x16x32_bf16(ah[0], bw2[0], zero, 0, 0, 0);
    o = __builtin_amdgcn_mfma_f32_16x16x32_bf16(ah[1], bw2[1], o, 0, 0, 0);
    if (cn == 0) {
        #pragma unroll
        for (int r = 0; r < 4; ++r) s_sig[wave][q*4+r] = o[r];
    }

    #pragma unroll
    for (int r = 0; r < 4; ++r)
        sB[(q*4+r)*PITCH + cn] = (unsigned short)f2bf(o[r]);
    short8 ov = *(const short8*)&sB[m*PITCH + (q >= 2 ? (q-2)*8 : 0)];

    union { unsigned u[4]; short8 s; } ci_hi, ci_lo;
    if (q < 2) {
        #pragma unroll
        for (int i = 0; i < 4; ++i) {
            float d0 = dv[2*i];
            float d1 = dv[2*i + 1];
            short h0 = f2bf(d0), h1 = f2bf(d1);
            ci_hi.u[i] = ((unsigned)(unsigned short)h1 << 16) | (unsigned)(unsigned short)h0;
            short l0 = f2bf(d0 - bf2f(h0)), l1 = f2bf(d1 - bf2f(h1));
            ci_lo.u[i] = ((unsigned)(unsigned short)l1 << 16) | (unsigned)(unsigned short)l0;
        }
    } else {
        ci_hi.s = ov;
        #pragma unroll
        for (int i = 0; i < 4; ++i) ci_lo.u[i] = 0u;
    }

    float4v hc[4];
    #pragma unroll
    for (int nt = 0; nt < 4; ++nt) {
        hc[nt] = __builtin_amdgcn_mfma_f32_16x16x32_bf16(ci_hi.s, bwc1[nt], zero, 0, 0, 0);
        hc[nt] = __builtin_amdgcn_mfma_f32_16x16x32_bf16(ci_lo.s, bwc1[nt], hc[nt], 0, 0, 0);
        #pragma unroll
        for (int r = 0; r < 4; ++r) hc[nt][r] = fmaxf(hc[nt][r], 0.f);
    }

    short8 bwc2[2][4], bwc3[2];
    #pragma unroll
    for (int c = 0; c < 2; ++c)
        #pragma unroll
        for (int nt = 0; nt < 4; ++nt)
            bwc2[c][nt] = ldfrag(wf, 10 + c*4 + nt, lane);
    #pragma unroll
    for (int c = 0; c < 2; ++c) bwc3[c] = ldfrag(wf, 18 + c, lane);

    #pragma unroll
    for (int nt = 0; nt < 4; ++nt)
        #pragma unroll
        for (int r = 0; r < 4; ++r) {
            float v = hc[nt][r];
            short hi = f2bf(v);
            sA[(q*4+r)*PITCH + nt*16 + cn] = (unsigned short)hi;
            sB[(q*4+r)*PITCH + nt*16 + cn] = (unsigned short)f2bf(v - bf2f(hi));
        }
    short8 ghi[2], glo[2];
    #pragma unroll
    for (int c = 0; c < 2; ++c) {
        ghi[c] = *(const short8*)&sA[m*PITCH + c*32 + q*8];
        glo[c] = *(const short8*)&sB[m*PITCH + c*32 + q*8];
    }

    float4v g[4];
    #pragma unroll
    for (int nt = 0; nt < 4; ++nt) {
        float4v acc = __builtin_amdgcn_mfma_f32_16x16x32_bf16(ghi[0], bwc2[0][nt], zero, 0, 0, 0);
        acc = __builtin_amdgcn_mfma_f32_16x16x32_bf16(glo[0], bwc2[0][nt], acc, 0, 0, 0);
        acc = __builtin_amdgcn_mfma_f32_16x16x32_bf16(ghi[1], bwc2[1][nt], acc, 0, 0, 0);
        acc = __builtin_amdgcn_mfma_f32_16x16x32_bf16(glo[1], bwc2[1][nt], acc, 0, 0, 0);
        #pragma unroll
        for (int r = 0; r < 4; ++r) acc[r] = fmaxf(acc[r], 0.f);
        g[nt] = acc;
    }

    #pragma unroll
    for (int nt = 0; nt < 4; ++nt)
        #pragma unroll
        for (int r = 0; r < 4; ++r) {
            float v = g[nt][r];
            short hi = f2bf(v);
            sA[(q*4+r)*PITCH + nt*16 + cn] = (unsigned short)hi;
            sB[(q*4+r)*PITCH + nt*16 + cn] = (unsigned short)f2bf(v - bf2f(hi));
        }
    short8 uhi[2], ulo[2];
    #pragma unroll
    for (int c = 0; c < 2; ++c) {
        uhi[c] = *(const short8*)&sA[m*PITCH + c*32 + q*8];
        ulo[c] = *(const short8*)&sB[m*PITCH + c*32 + q*8];
    }

    float4v col = __builtin_amdgcn_mfma_f32_16x16x32_bf16(uhi[0], bwc3[0], zero, 0, 0, 0);
    col = __builtin_amdgcn_mfma_f32_16x16x32_bf16(ulo[0], bwc3[0], col, 0, 0, 0);
    col = __builtin_amdgcn_mfma_f32_16x16x32_bf16(uhi[1], bwc3[1], col, 0, 0, 0);
    col = __builtin_amdgcn_mfma_f32_16x16x32_bf16(ulo[1], bwc3[1], col, 0, 0, 0);
    #pragma unroll
    for (int r = 0; r < 4; ++r)
        col[r] = 1.f / (1.f + __expf(-col[r]));

    if (cn < 3) {
        #pragma unroll
        for (int r = 0; r < 4; ++r) s_col[wave][q*4+r][cn] = col[r];
    }

    __builtin_amdgcn_s_waitcnt(0);
    int pfi = lane >> 2, c4 = lane & 3;
    int pout = blk + wave*16 + pfi;
    if (pout < n) {
        float v = (c4 == 3) ? s_sig[wave][pfi] : s_col[wave][pfi][c4];
        out[(size_t)pout*4 + c4] = v;
    }
}

// ================= pipeline kernels =================
__global__ __launch_bounds__(BLOCK)
void enc_chunk(const float4* __restrict__ pos4, const unsigned* __restrict__ tball,
               unsigned* __restrict__ encu, int n, int base, int len, int byAc)
{
    enc_body((int)blockIdx.x, (int)blockIdx.y, base, len, byAc, pos4, tball, encu, n);
}

// mix: row r is enc (chunk [encBase,encBase+encLen)) or mlp (chunk [mlpBase,mlpEnd))
// via Bresenham interleave of E enc rows among R total rows.
// NOTE: encu non-const (enc role writes; mlp role reads).
__global__ __launch_bounds__(BLOCK)
void mix_kernel(const float* __restrict__ x, const float4* __restrict__ pos4,
                const unsigned* __restrict__ tbu, unsigned* __restrict__ encu,
                const uint4* __restrict__ wf, float* __restrict__ out, int n,
                int encBase, int encLen, int byAc, int E, int R,
                int mlpBase, int mlpEnd)
{
    const int r = blockIdx.y;
    const int er  = (int)(((long long)r     * E) / R);
    const int er1 = (int)(((long long)(r+1) * E) / R);
    if (er1 > er) {
        enc_body((int)blockIdx.x, er, encBase, encLen, byAc, pos4, tbu, encu, n);
    } else {
        int mrow = r - er;
        int blk = mlpBase + (mrow*8 + (int)blockIdx.x)*64;
        if (blk >= mlpEnd) return;
        mlp_body(x, pos4, tbu, encu, wf, out, n, blk);
    }
}

__global__ __launch_bounds__(BLOCK)
void mlp_chunk(const float* __restrict__ x, const float4* __restrict__ pos4,
               const unsigned* __restrict__ tbu, const unsigned* __restrict__ encu,
               const uint4* __restrict__ wf, float* __restrict__ out, int n,
               int pbase, int pend)
{
    int blk = pbase + (int)blockIdx.x*64;
    if (blk >= pend) return;
    mlp_body(x, pos4, tbu, encu, wf, out, n, blk);
}

// ================= launch =================
extern "C" void kernel_launch(void* const* d_in, const int* in_sizes, int n_in,
                              void* d_out, int out_size, void* d_ws, size_t ws_size,
                              hipStream_t stream) {
    const float* x     = (const float*)d_in[0];
    const float* grids = (const float*)d_in[1];
    const float* w1    = (const float*)d_in[2];
    const float* w2    = (const float*)d_in[3];
    const float* wc1   = (const float*)d_in[4];
    const float* wc2   = (const float*)d_in[5];
    const float* wc3   = (const float*)d_in[6];
    float* out = (float*)d_out;

    int n = in_sizes[0] / 19;
    size_t encB = (size_t)16 * n * sizeof(unsigned);       // 64 MB
    size_t posB = (size_t)n * sizeof(float4);              // 16 MB
    size_t tabB = (size_t)NTAB * sizeof(unsigned);         // 33.5 MB

    char* p = (char*)d_ws;
    unsigned* encu = (unsigned*)p;
    float4*   pos4 = (float4*)(p + encB);
    unsigned* tbu  = (unsigned*)(p + encB + posB);
    uint4*    wf   = (uint4*)(p + encB + posB + tabB);

    int nTabBlk = (NTAB/2 + BLOCK - 1) / BLOCK;            // 2 entries/lane
    int nPosBlk = (n + BLOCK - 1) / BLOCK;
    prep_all<<<nTabBlk + nPosBlk + 1, BLOCK, 0, stream>>>(
        x, grids, w1, w2, wc1, wc2, wc3, pos4, tbu, wf, n, nTabBlk, nPosBlk);

    // 4-chunk pipeline: enc(c0); mix(enc c | mlp c-1) x3; mlp(c3).
    const int NCH = 4;
    int nc = ((n + NCH - 1) / NCH + 1023) & ~1023;         // chunk size, x1024
    int cb[NCH+1];
    for (int i = 0; i <= NCH; ++i) {
        long long b = (long long)i * nc;
        cb[i] = (int)(b < n ? b : n);
    }

    auto encRows = [&](int len, int& byAc) {
        byAc = (len + BLOCK*4 - 1) / (BLOCK*4);
        int q4 = (len + 3) / 4;
        int byBc = (q4 + BLOCK*4 - 1) / (BLOCK*4);
        return byAc + byBc;
    };

    // enc chunk 0
    {
        int len0 = cb[1] - cb[0];
        if (len0 > 0) {
            int byA0; int E0 = encRows(len0, byA0);
            enc_chunk<<<dim3(8, E0), BLOCK, 0, stream>>>(pos4, tbu, encu, n, cb[0], len0, byA0);
        }
    }
    // mixed middle stages
    for (int c = 1; c < NCH; ++c) {
        int lenE = cb[c+1] - cb[c];
        int lenM = cb[c] - cb[c-1];
        int Mrows = (lenM + 511) / 512;
        if (lenE > 0 && lenM > 0) {
            int byAc; int E = encRows(lenE, byAc);
            int R = E + Mrows;
            mix_kernel<<<dim3(8, R), BLOCK, 0, stream>>>(
                x, pos4, tbu, encu, wf, out, n,
                cb[c], lenE, byAc, E, R, cb[c-1], cb[c]);
        } else if (lenM > 0) {
            mlp_chunk<<<dim3(Mrows*8), BLOCK, 0, stream>>>(
                x, pos4, tbu, encu, wf, out, n, cb[c-1], cb[c]);
        } else if (lenE > 0) {
            int byAc; int E = encRows(lenE, byAc);
            enc_chunk<<<dim3(8, E), BLOCK, 0, stream>>>(pos4, tbu, encu, n, cb[c], lenE, byAc);
        }
    }
    // mlp tail chunk
    {
        int lenT = cb[NCH] - cb[NCH-1];
        if (lenT > 0) {
            int Mt = (lenT + 63) / 64;
            mlp_chunk<<<dim3(Mt), BLOCK, 0, stream>>>(
                x, pos4, tbu, encu, wf, out, n, cb[NCH-1], cb[NCH]);
        }
    }
}

// Round 7
// 516.328 us; speedup vs baseline: 1.1723x; 1.1469x over previous
//
#include <hip/hip_runtime.h>
#include <hip/hip_bf16.h>
#include <math.h>

// Round 13: revert to serial 3-launch structure (round 9 = best verified 532us);
// overlap abandoned (rounds 11/12: mix == serial; mechanism: enc streams +
// mlp hot tables exceed 4MB/XCD L2 -> thrash).
// Kept from round 12: slim mlp LDS (PITCH 72, no s_dir, 21248B -> 7 blk/CU),
// hoisted dv/encu loads, vectorized conv_tables.
// New: f2bf via __float2bfloat16 (single v_cvt instr, RNE identical to manual
// formula) -- cuts ~140 VALU ops/lane in mlp's convert/split chains.
// Reference bug replicated: final trilerp is c0*(1-fz) + c1*fy (fy, not fz).

#define BLOCK 256
#define NTAB  (16*524288)
#define PITCH 72

constexpr int      kNL[16] = {16,22,28,37,49,65,85,112,148,195,257,338,446,589,777,1025};
constexpr unsigned kSZ[16] = {4096u,10648u,21952u,50656u,117656u,274632u,
                              524288u,524288u,524288u,524288u,524288u,
                              524288u,524288u,524288u,524288u,524288u};

typedef __attribute__((ext_vector_type(8))) short short8;
typedef __attribute__((ext_vector_type(4))) float float4v;

__device__ __forceinline__ short f2bf(float f) {
    __hip_bfloat16 h = __float2bfloat16(f);   // RNE, single v_cvt instr
    union { __hip_bfloat16 b; short s; } cv; cv.b = h;
    return cv.s;
}
__device__ __forceinline__ float bf2f(short h) {
    return __uint_as_float(((unsigned)(unsigned short)h) << 16);
}
__device__ __forceinline__ unsigned pk2(float a, float b) {
    return ((unsigned)(unsigned short)f2bf(b) << 16) | (unsigned)(unsigned short)f2bf(a);
}
// packed table entry: lo16 = feat0, hi16 = feat1 (bf16)
__device__ __forceinline__ float pe0(unsigned u) { return __uint_as_float(u << 16); }
__device__ __forceinline__ float pe1(unsigned u) { return __uint_as_float(u & 0xffff0000u); }

// trilerp over 8 packed corners; vv[c]=x0 corners (y,z)=(c>>1,c&1), vv[4+c]=x1.
__device__ __forceinline__ unsigned trilerp_pack(const unsigned* vv, float fx, float fy, float fz)
{
    const float w0x = 1.f-fx, w0y = 1.f-fy, w0z = 1.f-fz;
    float e0, e1;
    {
        float c00 = pe0(vv[0])*w0x + pe0(vv[4])*fx;
        float c01 = pe0(vv[1])*w0x + pe0(vv[5])*fx;
        float c10 = pe0(vv[2])*w0x + pe0(vv[6])*fx;
        float c11 = pe0(vv[3])*w0x + pe0(vv[7])*fx;
        float c0 = c00*w0y + c10*fy;
        float c1 = c01*w0y + c11*fy;
        e0 = c0*w0z + c1*fy;   // reference bug: fy (not fz)
    }
    {
        float c00 = pe1(vv[0])*w0x + pe1(vv[4])*fx;
        float c01 = pe1(vv[1])*w0x + pe1(vv[5])*fx;
        float c10 = pe1(vv[2])*w0x + pe1(vv[6])*fx;
        float c11 = pe1(vv[3])*w0x + pe1(vv[7])*fx;
        float c0 = c00*w0y + c10*fy;
        float c1 = c01*w0y + c11*fy;
        e1 = c0*w0z + c1*fy;   // reference bug: fy (not fz)
    }
    return pk2(e0, e1);
}

// ================= merged prep kernel =================
__global__ __launch_bounds__(BLOCK)
void prep_all(const float* __restrict__ x, const float* __restrict__ grids,
              const float* __restrict__ w1, const float* __restrict__ w2,
              const float* __restrict__ wc1, const float* __restrict__ wc2,
              const float* __restrict__ wc3,
              float4* __restrict__ pos4, unsigned* __restrict__ tbu,
              uint4* __restrict__ wf, int n, int nTabBlk, int nPosBlk)
{
    const int b = blockIdx.x;
    if (b < nTabBlk) {
        int i = b * BLOCK + threadIdx.x;           // 2 entries per lane
        if (i < NTAB/2) {
            float4 v = ((const float4*)grids)[i];
            uint2 o;
            o.x = pk2(v.x, v.y);
            o.y = pk2(v.z, v.w);
            ((uint2*)tbu)[i] = o;
        }
    } else if (b < nTabBlk + nPosBlk) {
        int i = (b - nTabBlk) * BLOCK + threadIdx.x;
        if (i < n) {
            const float* xr = x + (size_t)i * 19;
            pos4[i] = make_float4(xr[0], xr[1], xr[2], 0.f);
        }
    } else {
        int lane = threadIdx.x;
        if (lane < 64) {
            int cn = lane & 15, q = lane >> 4;
            auto pack8 = [](const float* src, int stride) -> uint4 {
                uint4 r;
                r.x = pk2(src[0*stride], src[1*stride]);
                r.y = pk2(src[2*stride], src[3*stride]);
                r.z = pk2(src[4*stride], src[5*stride]);
                r.w = pk2(src[6*stride], src[7*stride]);
                return r;
            };
            int f = 0;
            for (int nt = 0; nt < 4; ++nt)
                wf[(f++)*64 + lane] = pack8(w1 + (q*8)*64 + nt*16 + cn, 64);
            for (int c = 0; c < 2; ++c)
                wf[(f++)*64 + lane] = pack8(w2 + (c*32 + q*8)*16 + cn, 16);
            for (int nt = 0; nt < 4; ++nt)
                wf[(f++)*64 + lane] = pack8(wc1 + (q*8)*64 + nt*16 + cn, 64);
            for (int c = 0; c < 2; ++c)
                for (int nt = 0; nt < 4; ++nt)
                    wf[(f++)*64 + lane] = pack8(wc2 + (c*32 + q*8)*64 + nt*16 + cn, 64);
            for (int c = 0; c < 2; ++c) {
                if (cn < 3) wf[(f++)*64 + lane] = pack8(wc3 + (c*32 + q*8)*3 + cn, 3);
                else { uint4 z; z.x = z.y = z.z = z.w = 0u; wf[(f++)*64 + lane] = z; }
            }
        }
    }
}

// ================= encode (levels 6..15) =================
template<int L>
__device__ __forceinline__ void gather4(const float4* __restrict__ pos4,
                                        const unsigned* __restrict__ tball,
                                        unsigned* __restrict__ encu,
                                        int n, int p0, int cnt)
{
    constexpr unsigned S = kSZ[L];
    constexpr unsigned H2c = 2654435761u, H3c = 805459861u;
    const unsigned* __restrict__ tbu = tball + (size_t)L * 524288u;

    unsigned vv[4][8];
    float fxa[4], fya[4], fza[4];
    #pragma unroll
    for (int q = 0; q < 4; ++q) {
        if (q >= cnt) continue;
        float4 p = pos4[p0+q];
        const float Rf = (float)kNL[L];
        float ux = p.x*Rf, uy = p.y*Rf, uz = p.z*Rf;
        float gx = floorf(ux), gy = floorf(uy), gz = floorf(uz);
        fxa[q] = ux-gx; fya[q] = uy-gy; fza[q] = uz-gz;
        int ix = (int)gx, iy = (int)gy, iz = (int)gz;

        unsigned tc[4];
        #pragma unroll
        for (int c = 0; c < 4; ++c) {
            int yb = c >> 1, zb = c & 1;
            tc[c] = (unsigned)(iy+yb)*H2c ^ (unsigned)(iz+zb)*H3c;
        }
        if ((ix & 1) == 0) {
            #pragma unroll
            for (int c = 0; c < 4; ++c) {
                unsigned idx0 = ((unsigned)ix ^ tc[c]) & (S-1u);
                uint2 pr = *(const uint2*)(tbu + (idx0 & ~1u));
                unsigned swp = idx0 & 1u;
                vv[q][c]   = swp ? pr.y : pr.x;   // corner x=ix
                vv[q][4+c] = swp ? pr.x : pr.y;   // corner x=ix+1
            }
        } else {
            #pragma unroll
            for (int c = 0; c < 4; ++c) {
                unsigned idx0 = ((unsigned)ix     ^ tc[c]) & (S-1u);
                unsigned idx1 = ((unsigned)(ix+1) ^ tc[c]) & (S-1u);
                vv[q][c]   = tbu[idx0];
                vv[q][4+c] = tbu[idx1];
            }
        }
    }

    unsigned pkd[4];
    #pragma unroll
    for (int q = 0; q < 4; ++q) {
        if (q >= cnt) continue;
        pkd[q] = trilerp_pack(vv[q], fxa[q], fya[q], fza[q]);
    }

    unsigned* d = encu + (size_t)L*n + p0;
    if (cnt == 4) {
        uint4 o; o.x = pkd[0]; o.y = pkd[1]; o.z = pkd[2]; o.w = pkd[3];
        *(uint4*)d = o;
    } else {
        for (int q = 0; q < cnt; ++q) d[q] = pkd[q];
    }
}

// merged encode: phase A (levels 6..13 XCD-pinned), phase B (14/15 on 4 XCDs
// each, quarter points). Levels 0..5 are computed inside mlp_mfma.
__global__ __launch_bounds__(BLOCK)
void enc_all(const float4* __restrict__ pos4, const unsigned* __restrict__ tball,
             unsigned* __restrict__ encu, int n, int byA)
{
    const int bx = blockIdx.x;   // == XCD (linear id % 8)
    const int by = blockIdx.y;

    if (by < byA) {
        int p0 = (by*BLOCK + threadIdx.x) * 4;
        if (p0 >= n) return;
        int cnt = min(4, n - p0);
        switch (bx) {
            case 0: gather4< 6>(pos4,tball,encu,n,p0,cnt); break;
            case 1: gather4< 7>(pos4,tball,encu,n,p0,cnt); break;
            case 2: gather4< 8>(pos4,tball,encu,n,p0,cnt); break;
            case 3: gather4< 9>(pos4,tball,encu,n,p0,cnt); break;
            case 4: gather4<10>(pos4,tball,encu,n,p0,cnt); break;
            case 5: gather4<11>(pos4,tball,encu,n,p0,cnt); break;
            case 6: gather4<12>(pos4,tball,encu,n,p0,cnt); break;
            case 7: gather4<13>(pos4,tball,encu,n,p0,cnt); break;
        }
    } else {
        int q4 = (n + 3) / 4;
        int quarter = bx & 3;
        int jb = quarter * q4;
        int je = min(n, jb + q4);
        int p0 = jb + ((by-byA)*BLOCK + threadIdx.x) * 4;
        if (p0 >= je) return;
        int cnt = min(4, je - p0);
        if (bx < 4) gather4<14>(pos4,tball,encu,n,p0,cnt);
        else        gather4<15>(pos4,tball,encu,n,p0,cnt);
    }
}

// ---- levels 0..5 single-point address/issue phase (loads only) ----
template<int LV>
__device__ __forceinline__ void enc_addr(float4 p, const unsigned* __restrict__ tball,
                                         unsigned vv[8], float& fx, float& fy, float& fz)
{
    constexpr int R = kNL[LV];
    constexpr unsigned S = kSZ[LV];
    constexpr unsigned H2c = 2654435761u, H3c = 805459861u;
    const unsigned* __restrict__ tb = tball + (size_t)LV * 524288u;
    const float Rf = (float)R;
    float ux = p.x*Rf, uy = p.y*Rf, uz = p.z*Rf;
    float gx = floorf(ux), gy = floorf(uy), gz = floorf(uz);
    fx = ux-gx; fy = uy-gy; fz = uz-gz;
    int ix = (int)gx, iy = (int)gy, iz = (int)gz;

    if (LV >= 3) {
        unsigned tc[4];
        #pragma unroll
        for (int c = 0; c < 4; ++c) {
            int yb = c >> 1, zb = c & 1;
            tc[c] = (unsigned)(iy+yb)*H2c ^ (unsigned)(iz+zb)*H3c;
        }
        if ((ix & 1) == 0) {
            #pragma unroll
            for (int c = 0; c < 4; ++c) {
                unsigned h0 = (unsigned)ix ^ tc[c];
                unsigned base = (h0 & ~1u) % S;          // even, base+1 < S
                uint2 pr = *(const uint2*)(tb + base);
                unsigned swp = h0 & 1u;
                vv[c]   = swp ? pr.y : pr.x;             // corner x=ix
                vv[4+c] = swp ? pr.x : pr.y;             // corner x=ix+1
            }
        } else {
            #pragma unroll
            for (int c = 0; c < 4; ++c) {
                vv[c]   = tb[(((unsigned)ix)     ^ tc[c]) % S];
                vv[4+c] = tb[(((unsigned)(ix+1)) ^ tc[c]) % S];
            }
        }
    } else {
        #pragma unroll
        for (int j = 0; j < 8; ++j) {
            int ox = ix + ((j>>2)&1);
            int oy = iy + ((j>>1)&1);
            int oz = iz + (j&1);
            vv[j] = tb[(unsigned)((oz*(R*R) + oy*R + ox) % (int)S)];
        }
    }
}

// ================= MFMA MLP =================
__device__ __forceinline__ short8 ldfrag(const uint4* __restrict__ wf, int f, int lane) {
    union { uint4 u; short8 s; } cv;
    cv.u = wf[f*64 + lane];
    return cv.s;
}

__global__ __launch_bounds__(BLOCK)
void mlp_mfma(const float* __restrict__ x,
              const float4* __restrict__ pos4,
              const unsigned* __restrict__ tbu,
              const unsigned* __restrict__ encu,
              const uint4* __restrict__ wf,
              float* __restrict__ out, int n)
{
    __shared__ unsigned short s_scr[4][2][16*PITCH];   // 18432 B
    __shared__ float s_sig[4][16];                     //   256 B
    __shared__ float s_col[4][16][4];                  //  1024 B
    __shared__ unsigned s_lowB[6][64];                 //  1536 B  (21248 total)

    const int t = threadIdx.x;
    const int lane = t & 63;
    const int wave = t >> 6;
    const int m = lane & 15;
    const int q = lane >> 4;
    const int cn = m;
    const int blk = blockIdx.x * 64;
    const int pt  = blk + wave*16 + m;
    const int ptc = pt < n ? pt : n - 1;

    const float4v zero = {0.f, 0.f, 0.f, 0.f};

    // ---- hoisted independent loads: encu levels + direction floats ----
    unsigned encv[4];
    #pragma unroll
    for (int i = 0; i < 4; ++i) {
        int lv = q*4 + i;
        if (lv >= 6) encv[i] = encu[(size_t)lv*n + ptc];
    }
    float dv[8];
    if (q < 2) {
        #pragma unroll
        for (int i = 0; i < 8; ++i)
            dv[i] = x[(size_t)ptc*19 + 3 + q*8 + i];
    }

    // ---- levels 0..5 for this block's 64 points, wave-uniform level ----
    {
        int pp = blk + lane; if (pp >= n) pp = n - 1;
        float4 p = pos4[pp];
        unsigned vv[8]; float fx, fy, fz;
        switch (wave) {
            case 0:  enc_addr<0>(p, tbu, vv, fx, fy, fz); break;
            case 1:  enc_addr<1>(p, tbu, vv, fx, fy, fz); break;
            case 2:  enc_addr<2>(p, tbu, vv, fx, fy, fz); break;
            default: enc_addr<3>(p, tbu, vv, fx, fy, fz); break;
        }
        s_lowB[wave][lane] = trilerp_pack(vv, fx, fy, fz);
    }
    if (lane < 32) {
        int lv = 4 + (wave >> 1);
        int pb2 = (wave & 1)*32 + lane;      // 0..63 within block
        int pp = blk + pb2; if (pp >= n) pp = n - 1;
        float4 p = pos4[pp];
        unsigned vv[8]; float fx, fy, fz;
        if (lv == 4) enc_addr<4>(p, tbu, vv, fx, fy, fz);
        else         enc_addr<5>(p, tbu, vv, fx, fy, fz);
        s_lowB[lv][pb2] = trilerp_pack(vv, fx, fy, fz);
    }
    __syncthreads();

    // ---- layer-1 A fragment: levels q*4..q*4+3 ----
    union { unsigned u[4]; short8 s; } a1;
    #pragma unroll
    for (int i = 0; i < 4; ++i) {
        int lv = q*4 + i;
        if (lv < 6) a1.u[i] = s_lowB[lv][wave*16 + m];
        else        a1.u[i] = encv[i];
    }

    short8 bw1[4], bw2[2], bwc1[4];
    #pragma unroll
    for (int nt = 0; nt < 4; ++nt) bw1[nt] = ldfrag(wf, nt, lane);
    #pragma unroll
    for (int c = 0; c < 2; ++c)    bw2[c]  = ldfrag(wf, 4 + c, lane);
    #pragma unroll
    for (int nt = 0; nt < 4; ++nt) bwc1[nt] = ldfrag(wf, 6 + nt, lane);

    float4v h[4];
    #pragma unroll
    for (int nt = 0; nt < 4; ++nt) {
        h[nt] = __builtin_amdgcn_mfma_f32_16x16x32_bf16(a1.s, bw1[nt], zero, 0, 0, 0);
        #pragma unroll
        for (int r = 0; r < 4; ++r) h[nt][r] = fmaxf(h[nt][r], 0.f);
    }

    unsigned short* sA = &s_scr[wave][0][0];
    unsigned short* sB = &s_scr[wave][1][0];
    #pragma unroll
    for (int nt = 0; nt < 4; ++nt)
        #pragma unroll
        for (int r = 0; r < 4; ++r)
            sA[(q*4+r)*PITCH + nt*16 + cn] = (unsigned short)f2bf(h[nt][r]);
    short8 ah[2];
    #pragma unroll
    for (int c = 0; c < 2; ++c)
        ah[c] = *(const short8*)&sA[m*PITCH + c*32 + q*8];

    float4v o = __builtin_amdgcn_mfma_f32_16x16x32_bf16(ah[0], bw2[0], zero, 0, 0, 0);
    o = __builtin_amdgcn_mfma_f32_16x16x32_bf16(ah[1], bw2[1], o, 0, 0, 0);
    if (cn == 0) {
        #pragma unroll
        for (int r = 0; r < 4; ++r) s_sig[wave][q*4+r] = o[r];
    }

    #pragma unroll
    for (int r = 0; r < 4; ++r)
        sB[(q*4+r)*PITCH + cn] = (unsigned short)f2bf(o[r]);
    short8 ov = *(const short8*)&sB[m*PITCH + (q >= 2 ? (q-2)*8 : 0)];

    union { unsigned u[4]; short8 s; } ci_hi, ci_lo;
    if (q < 2) {
        #pragma unroll
        for (int i = 0; i < 4; ++i) {
            float d0 = dv[2*i];
            float d1 = dv[2*i + 1];
            short h0 = f2bf(d0), h1 = f2bf(d1);
            ci_hi.u[i] = ((unsigned)(unsigned short)h1 << 16) | (unsigned)(unsigned short)h0;
            short l0 = f2bf(d0 - bf2f(h0)), l1 = f2bf(d1 - bf2f(h1));
            ci_lo.u[i] = ((unsigned)(unsigned short)l1 << 16) | (unsigned)(unsigned short)l0;
        }
    } else {
        ci_hi.s = ov;
        #pragma unroll
        for (int i = 0; i < 4; ++i) ci_lo.u[i] = 0u;
    }

    float4v hc[4];
    #pragma unroll
    for (int nt = 0; nt < 4; ++nt) {
        hc[nt] = __builtin_amdgcn_mfma_f32_16x16x32_bf16(ci_hi.s, bwc1[nt], zero, 0, 0, 0);
        hc[nt] = __builtin_amdgcn_mfma_f32_16x16x32_bf16(ci_lo.s, bwc1[nt], hc[nt], 0, 0, 0);
        #pragma unroll
        for (int r = 0; r < 4; ++r) hc[nt][r] = fmaxf(hc[nt][r], 0.f);
    }

    short8 bwc2[2][4], bwc3[2];
    #pragma unroll
    for (int c = 0; c < 2; ++c)
        #pragma unroll
        for (int nt = 0; nt < 4; ++nt)
            bwc2[c][nt] = ldfrag(wf, 10 + c*4 + nt, lane);
    #pragma unroll
    for (int c = 0; c < 2; ++c) bwc3[c] = ldfrag(wf, 18 + c, lane);

    #pragma unroll
    for (int nt = 0; nt < 4; ++nt)
        #pragma unroll
        for (int r = 0; r < 4; ++r) {
            float v = hc[nt][r];
            short hi = f2bf(v);
            sA[(q*4+r)*PITCH + nt*16 + cn] = (unsigned short)hi;
            sB[(q*4+r)*PITCH + nt*16 + cn] = (unsigned short)f2bf(v - bf2f(hi));
        }
    short8 ghi[2], glo[2];
    #pragma unroll
    for (int c = 0; c < 2; ++c) {
        ghi[c] = *(const short8*)&sA[m*PITCH + c*32 + q*8];
        glo[c] = *(const short8*)&sB[m*PITCH + c*32 + q*8];
    }

    float4v g[4];
    #pragma unroll
    for (int nt = 0; nt < 4; ++nt) {
        float4v acc = __builtin_amdgcn_mfma_f32_16x16x32_bf16(ghi[0], bwc2[0][nt], zero, 0, 0, 0);
        acc = __builtin_amdgcn_mfma_f32_16x16x32_bf16(glo[0], bwc2[0][nt], acc, 0, 0, 0);
        acc = __builtin_amdgcn_mfma_f32_16x16x32_bf16(ghi[1], bwc2[1][nt], acc, 0, 0, 0);
        acc = __builtin_amdgcn_mfma_f32_16x16x32_bf16(glo[1], bwc2[1][nt], acc, 0, 0, 0);
        #pragma unroll
        for (int r = 0; r < 4; ++r) acc[r] = fmaxf(acc[r], 0.f);
        g[nt] = acc;
    }

    #pragma unroll
    for (int nt = 0; nt < 4; ++nt)
        #pragma unroll
        for (int r = 0; r < 4; ++r) {
            float v = g[nt][r];
            short hi = f2bf(v);
            sA[(q*4+r)*PITCH + nt*16 + cn] = (unsigned short)hi;
            sB[(q*4+r)*PITCH + nt*16 + cn] = (unsigned short)f2bf(v - bf2f(hi));
        }
    short8 uhi[2], ulo[2];
    #pragma unroll
    for (int c = 0; c < 2; ++c) {
        uhi[c] = *(const short8*)&sA[m*PITCH + c*32 + q*8];
        ulo[c] = *(const short8*)&sB[m*PITCH + c*32 + q*8];
    }

    float4v col = __builtin_amdgcn_mfma_f32_16x16x32_bf16(uhi[0], bwc3[0], zero, 0, 0, 0);
    col = __builtin_amdgcn_mfma_f32_16x16x32_bf16(ulo[0], bwc3[0], col, 0, 0, 0);
    col = __builtin_amdgcn_mfma_f32_16x16x32_bf16(uhi[1], bwc3[1], col, 0, 0, 0);
    col = __builtin_amdgcn_mfma_f32_16x16x32_bf16(ulo[1], bwc3[1], col, 0, 0, 0);
    #pragma unroll
    for (int r = 0; r < 4; ++r)
        col[r] = 1.f / (1.f + __expf(-col[r]));

    if (cn < 3) {
        #pragma unroll
        for (int r = 0; r < 4; ++r) s_col[wave][q*4+r][cn] = col[r];
    }

    __builtin_amdgcn_s_waitcnt(0);
    int pfi = lane >> 2, c4 = lane & 3;
    int pout = blk + wave*16 + pfi;
    if (pout < n) {
        float v = (c4 == 3) ? s_sig[wave][pfi] : s_col[wave][pfi][c4];
        out[(size_t)pout*4 + c4] = v;
    }
}

// ================= launch =================
extern "C" void kernel_launch(void* const* d_in, const int* in_sizes, int n_in,
                              void* d_out, int out_size, void* d_ws, size_t ws_size,
                              hipStream_t stream) {
    const float* x     = (const float*)d_in[0];
    const float* grids = (const float*)d_in[1];
    const float* w1    = (const float*)d_in[2];
    const float* w2    = (const float*)d_in[3];
    const float* wc1   = (const float*)d_in[4];
    const float* wc2   = (const float*)d_in[5];
    const float* wc3   = (const float*)d_in[6];
    float* out = (float*)d_out;

    int n = in_sizes[0] / 19;
    size_t encB = (size_t)16 * n * sizeof(unsigned);       // 64 MB
    size_t posB = (size_t)n * sizeof(float4);              // 16 MB
    size_t tabB = (size_t)NTAB * sizeof(unsigned);         // 33.5 MB

    char* p = (char*)d_ws;
    unsigned* encu = (unsigned*)p;
    float4*   pos4 = (float4*)(p + encB);
    unsigned* tbu  = (unsigned*)(p + encB + posB);
    uint4*    wf   = (uint4*)(p + encB + posB + tabB);

    int nTabBlk = (NTAB/2 + BLOCK - 1) / BLOCK;            // 2 entries/lane
    int nPosBlk = (n + BLOCK - 1) / BLOCK;
    prep_all<<<nTabBlk + nPosBlk + 1, BLOCK, 0, stream>>>(
        x, grids, w1, w2, wc1, wc2, wc3, pos4, tbu, wf, n, nTabBlk, nPosBlk);

    int byA = (n + BLOCK*4 - 1) / (BLOCK*4);          // chunks of 1024 points
    int q4  = (n + 3) / 4;
    int byB = (q4 + BLOCK*4 - 1) / (BLOCK*4);
    dim3 ge(8, byA + byB);
    enc_all<<<ge, BLOCK, 0, stream>>>(pos4, tbu, encu, n, byA);

    mlp_mfma<<<(n + 63) / 64, BLOCK, 0, stream>>>(x, pos4, tbu, encu, wf, out, n);
}